// Round 1
// baseline (134.359 us; speedup 1.0000x reference)
//
#include <hip/hip_runtime.h>
#include <hip/hip_bf16.h>
#include <stdint.h>

// out = (x @ Wv + bv) @ Wo + bo          [all I/O f32]
// Deformable sampling is the identity: |tanh|*2/128 < 0.016 << 0.5 so
// round(samp)==coords; all 7 points sample token n; scores identical;
// softmax exactly uniform; out_h == v. Q/K/offset-MLP are dead code.
// Fused: out = x @ W' + b', W' = Wv@Wo (bf16), b' = bv@Wo + bo (f32).
//
// R6: k1 converts x->bf16 (xb) XCD-aligned instead of blind prefetch;
//     GEMM retiled 128x128 (BT L2 traffic halved, A-stream bf16+L2-local),
//     LDS double-buffered (1 barrier/iter), vectorized Wo staging.

typedef unsigned short u16;
typedef short bf16x8 __attribute__((ext_vector_type(8)));   // 8 bf16, 4 VGPRs
typedef u16 ushort8 __attribute__((ext_vector_type(8)));
typedef float f32x4 __attribute__((ext_vector_type(4)));

__device__ __forceinline__ u16 f2bf(float f) {
  __hip_bfloat16 h = __float2bfloat16(f);   // hw cvt, RNE
  union { __hip_bfloat16 h; u16 u; } v; v.h = h; return v.u;
}

// ws layout: [0,512K) W'^T bf16 ; [512K,640K) P bias partials f32 [64][512] ;
//            [1M, 1M+16.75M) xb = x as bf16 [16384][512]
#define WS_WPT 0
#define WS_P   524288
#define WS_XB  1048576

// ---------------------------------------------------------------------------
// blocks 0..63   : W'^T[n'][k'] = sum_m Wo[m][n'] * Wv[k'][m]   (bf16 out)
// blocks 64..127 : bias partials P[j][n] = sum_{m in 8j..8j+7} bv[m]*Wo[m][n]
// blocks 128..639: x -> bf16 (32 rows/block), mapped so each block's rows
//                  belong to the gemm m-slab whose XCD == this block's XCD
//                  (bid%8 == m_idx%8) => xb is L2-local for the gemm.
// ---------------------------------------------------------------------------
__global__ __launch_bounds__(256)
void precompose_fused(const float* __restrict__ Wv, const float* __restrict__ bv,
                      const float* __restrict__ Wo, const float* __restrict__ x,
                      u16* __restrict__ WpT, float* __restrict__ P,
                      u16* __restrict__ xb) {
  const int b = blockIdx.x;
  const int tid = threadIdx.x;

  if (b >= 128) {             // ---- x -> bf16 convert (XCD-aligned)
    const int jj = b - 128;               // 0..511
    const int t = jj & 7;                 // target XCD ( == b%8 since 128%8==0 )
    const int u = jj >> 3;                // 0..63
    const int m_idx = (u >> 2) * 8 + t;   // 0..127  (m_idx % 8 == t)
    const int chunk = u & 3;              // which 32-row quarter of the slab
    const int row0 = m_idx * 128 + chunk * 32;
    const float* __restrict__ src = x + (size_t)row0 * 512;
    u16* __restrict__ dst = xb + (size_t)row0 * 512;
#pragma unroll
    for (int it = 0; it < 8; ++it) {      // 32 rows * 512 = 16384 elems
      const int idx = it * 2048 + tid * 8;
      f32x4 a  = __builtin_nontemporal_load((const f32x4*)(src + idx));
      f32x4 c4 = __builtin_nontemporal_load((const f32x4*)(src + idx + 4));
      ushort8 o;
      o[0]=f2bf(a[0]);  o[1]=f2bf(a[1]);  o[2]=f2bf(a[2]);  o[3]=f2bf(a[3]);
      o[4]=f2bf(c4[0]); o[5]=f2bf(c4[1]); o[6]=f2bf(c4[2]); o[7]=f2bf(c4[3]);
      *(ushort8*)(dst + idx) = o;         // cached write -> stays in local L2
    }
    return;
  }

  if (b >= 64) {              // ---- bias partials (parallel over m-slices)
    const int j = b - 64;
    const int n = tid;
    float s0 = 0.f, s1 = 0.f;
#pragma unroll
    for (int mm = 0; mm < 8; ++mm) {
      const float bvm = bv[8 * j + mm];
      const float* w = Wo + (size_t)(8 * j + mm) * 512;
      s0 += bvm * w[n];
      s1 += bvm * w[n + 256];
    }
    P[(size_t)j * 512 + n] = s0;
    P[(size_t)j * 512 + n + 256] = s1;
    return;
  }

  // ---- W'^T 64x64 tile
  __shared__ u16 As[64 * 72];          // As[n'loc][mloc], stride 72
  __shared__ u16 Bs[64 * 72];          // Bs[k'loc][mloc], stride 72
  const int lane = tid & 63, wave = tid >> 6;
  const int wm = wave & 1, wn = wave >> 1;
  const int q = lane >> 4, lr = lane & 15;
  const int i0 = (b >> 3) * 64;        // n' tile
  const int j0 = (b & 7) * 64;         // k' tile

  f32x4 acc[2][2];
#pragma unroll
  for (int i = 0; i < 2; ++i)
#pragma unroll
    for (int j = 0; j < 2; ++j) { f32x4 z = {0.f,0.f,0.f,0.f}; acc[i][j] = z; }

  for (int m0 = 0; m0 < 512; m0 += 64) {
#pragma unroll
    for (int su = 0; su < 4; ++su) {   // transposed A stage, f32x4 loads
      const int s = su * 256 + tid;    // 0..1023
      const int mloc = s >> 4;         // 0..63
      const int nq = (s & 15) * 4;     // 0,4,..,60
      f32x4 w = *(const f32x4*)(Wo + (size_t)(m0 + mloc) * 512 + i0 + nq);
#pragma unroll
      for (int e = 0; e < 4; ++e)
        As[(nq + e) * 72 + mloc] = f2bf(w[e]);
    }
#pragma unroll
    for (int su = 0; su < 2; ++su) {   // B stage (vectorized)
      const int s = su * 256 + tid;
      const int row = s >> 3, p = s & 7;
      const float* sv = Wv + (size_t)(j0 + row) * 512 + m0 + p * 8;
      f32x4 a = *(const f32x4*)sv, c4 = *(const f32x4*)(sv + 4);
      ushort8 o;
      o[0]=f2bf(a[0]); o[1]=f2bf(a[1]); o[2]=f2bf(a[2]); o[3]=f2bf(a[3]);
      o[4]=f2bf(c4[0]); o[5]=f2bf(c4[1]); o[6]=f2bf(c4[2]); o[7]=f2bf(c4[3]);
      *(ushort8*)(Bs + row * 72 + p * 8) = o;
    }
    __syncthreads();

#pragma unroll
    for (int kk = 0; kk < 2; ++kk) {
      const int c = kk * 4 + q;
      bf16x8 af[2], bfr[2];
#pragma unroll
      for (int t = 0; t < 2; ++t) {
        af[t]  = *(const bf16x8*)(As + (wm * 32 + t * 16 + lr) * 72 + c * 8);
        bfr[t] = *(const bf16x8*)(Bs + (wn * 32 + t * 16 + lr) * 72 + c * 8);
      }
#pragma unroll
      for (int mt = 0; mt < 2; ++mt)
#pragma unroll
        for (int nt = 0; nt < 2; ++nt)
          acc[mt][nt] = __builtin_amdgcn_mfma_f32_16x16x32_bf16(
              af[mt], bfr[nt], acc[mt][nt], 0, 0, 0);
    }
    __syncthreads();
  }

  // D: col=lane&15, row=quad*4+reg
#pragma unroll
  for (int nt = 0; nt < 2; ++nt) {
    const int col = j0 + wn * 32 + nt * 16 + lr;
#pragma unroll
    for (int mt = 0; mt < 2; ++mt) {
      const int row0 = i0 + wm * 32 + mt * 16 + q * 4;
#pragma unroll
      for (int r = 0; r < 4; ++r)
        WpT[(size_t)(row0 + r) * 512 + col] = f2bf(acc[mt][nt][r]);
    }
  }
}

// ---------------------------------------------------------------------------
// out[M,512] f32 = xb[M,512] bf16 @ W' (+ b'), W' as BT[n][k] bf16.
// 128x128 tile, BK=64. Grid 512 (1-D): m_idx = bid & 127, n_idx = bid >> 7
//   => the 4 n-blocks of an m-slab are {m, m+128, m+256, m+384}: same id%8
//   => same XCD as the converter block that wrote those xb rows (L2 hit).
// L2 stream: xb 4x16.8=67MB + BT 512x128KB=67MB (was 265MB at 64x128/f32).
// LDS double-buffered (64.5KB, 2 blocks/CU = grid-resident), 1 barrier/iter.
// C written with nontemporal stores (never re-read; keep L2 for xb/BT).
// Accumulation order over K identical to the verified 64x128 version.
// ---------------------------------------------------------------------------
__global__ __launch_bounds__(256, 2)
void gemm_xb_bt(const u16* __restrict__ xb, const u16* __restrict__ BT,
                const float* __restrict__ P, const float* __restrict__ bo,
                float* __restrict__ C) {
  constexpr int BM = 128, BN = 128, BK = 64;
  __shared__ u16 As[2][BM * BK];       // xb tile, XOR-swizzled chunks
  __shared__ u16 Bs[2][BN * BK];       // W'^T tile
  __shared__ float bias_s[BN];

  const int tid = threadIdx.x;
  const int lane = tid & 63, wave = tid >> 6;
  const int wm = wave & 1, wn = wave >> 1;
  const int q = lane >> 4, lr = lane & 15;
  const int bid = blockIdx.x;
  const int m0 = (bid & 127) * BM;
  const int n0 = (bid >> 7) * BN;

  f32x4 acc[4][4];
#pragma unroll
  for (int i = 0; i < 4; ++i)
#pragma unroll
    for (int j = 0; j < 4; ++j) { f32x4 z = {0.f,0.f,0.f,0.f}; acc[i][j] = z; }

  ushort8 pa[4], pb[4];                // prefetched xb / BT (4 slots each)

  auto load_tile = [&](int k0) {
#pragma unroll
    for (int it = 0; it < 4; ++it) {   // 1024 slots each side
      const int s = it * 256 + tid;
      const int row = s >> 3, p = s & 7;
      const int c = p ^ (row & 7);
      pa[it] = *(const ushort8*)(xb + (size_t)(m0 + row) * 512 + k0 + c * 8);
      pb[it] = *(const ushort8*)(BT + (size_t)(n0 + row) * 512 + k0 + c * 8);
    }
  };
  auto store_tile = [&](int bi) {
#pragma unroll
    for (int it = 0; it < 4; ++it) {
      const int s = it * 256 + tid;
      *(ushort8*)(&As[bi][s * 8]) = pa[it];
      *(ushort8*)(&Bs[bi][s * 8]) = pb[it];
    }
  };
  auto compute = [&](int bi) {
#pragma unroll
    for (int kk = 0; kk < 2; ++kk) {
      const int c = kk * 4 + q;
      bf16x8 af[4], bfr[4];
#pragma unroll
      for (int t = 0; t < 4; ++t) {
        const int rowA = wm * 64 + t * 16 + lr;
        af[t] = *(const bf16x8*)(&As[bi][rowA * BK + (c ^ (rowA & 7)) * 8]);
        const int rowB = wn * 64 + t * 16 + lr;
        bfr[t] = *(const bf16x8*)(&Bs[bi][rowB * BK + (c ^ (rowB & 7)) * 8]);
      }
#pragma unroll
      for (int mt = 0; mt < 4; ++mt)
#pragma unroll
        for (int nt = 0; nt < 4; ++nt)
          acc[mt][nt] = __builtin_amdgcn_mfma_f32_16x16x32_bf16(
              af[mt], bfr[nt], acc[mt][nt], 0, 0, 0);
    }
  };

  // prologue: issue tile-0 loads; overlap bias reduction with them
  load_tile(0);
  if (tid < BN) {
    float s = bo[n0 + tid];
#pragma unroll 8
    for (int j = 0; j < 64; ++j) s += P[(size_t)j * 512 + n0 + tid];
    bias_s[tid] = s;
  }
  store_tile(0);
  __syncthreads();

  // double-buffered: tile k lives in buf (k&1); 1 barrier per iteration
  for (int k = 1; k < 8; ++k) {
    load_tile(k * 64);                 // next tile into regs (in flight)
    compute((k - 1) & 1);              // consume previous tile
    store_tile(k & 1);                 // regs -> other LDS buffer
    __syncthreads();
  }
  compute(1);                          // tile 7 is in buf 1

  // D: col=lane&15, row=quad*4+reg; nontemporal f32 stores
#pragma unroll
  for (int nt = 0; nt < 4; ++nt) {
    const int lcol = wn * 64 + nt * 16 + lr;
    const float bsv = bias_s[lcol];
#pragma unroll
    for (int mt = 0; mt < 4; ++mt) {
      const int grow0 = m0 + wm * 64 + mt * 16 + q * 4;
#pragma unroll
      for (int r = 0; r < 4; ++r)
        __builtin_nontemporal_store(acc[mt][nt][r] + bsv,
                                    C + (size_t)(grow0 + r) * 512 + n0 + lcol);
    }
  }
}

// ---------------------------------------------------------------------------
extern "C" void kernel_launch(void* const* d_in, const int* in_sizes, int n_in,
                              void* d_out, int out_size, void* d_ws, size_t ws_size,
                              hipStream_t stream) {
  // 0:x 1:H 2:W 3:Wq 4:bq 5:Wk 6:bk 7:Wv 8:bv 9:Wo 10:bo 11..14 offsets(dead)
  const float* x  = (const float*)d_in[0];
  const float* Wv = (const float*)d_in[7];
  const float* bv = (const float*)d_in[8];
  const float* Wo = (const float*)d_in[9];
  const float* bo = (const float*)d_in[10];
  float* outp = (float*)d_out;

  u16*   WpT = (u16*)((uint8_t*)d_ws + WS_WPT);
  float* P   = (float*)((uint8_t*)d_ws + WS_P);
  u16*   xb  = (u16*)((uint8_t*)d_ws + WS_XB);

  precompose_fused<<<640, 256, 0, stream>>>(Wv, bv, Wo, x, WpT, P, xb);
  gemm_xb_bt<<<512, 256, 0, stream>>>(xb, WpT, P, bo, outp);
}

// Round 2
// 131.142 us; speedup vs baseline: 1.0245x; 1.0245x over previous
//
#include <hip/hip_runtime.h>
#include <hip/hip_bf16.h>
#include <stdint.h>

// out = (x @ Wv + bv) @ Wo + bo          [all I/O f32]
// Deformable sampling is the identity: |tanh|*2/128 < 0.016 << 0.5 so
// round(samp)==coords; all 7 points sample token n; scores identical;
// softmax exactly uniform; out_h == v. Q/K/offset-MLP are dead code.
// Fused: out = x @ W' + b', W' = Wv@Wo (bf16), b' = bv@Wo + bo (f32).
//
// R7: revert to the verified R5 structure (130.0 us). Only retained change
// from R6: f32x4-vectorized Wo staging in the W'^T tile (VALU-bound stage,
// identical numerics). R6 post-mortem: xb conversion + 128x128 dbuf tile was
// neutral (x already L3-hot; occupancy 4->2 blocks/CU cancelled the traffic
// saving); the apparent +4us was mostly fill-noise (fills 41.7->43.2 us).

typedef unsigned short u16;
typedef short bf16x8 __attribute__((ext_vector_type(8)));   // 8 bf16, 4 VGPRs
typedef u16 ushort8 __attribute__((ext_vector_type(8)));
typedef float f32x4 __attribute__((ext_vector_type(4)));

__device__ __forceinline__ u16 f2bf(float f) {
  __hip_bfloat16 h = __float2bfloat16(f);   // hw cvt, RNE
  union { __hip_bfloat16 h; u16 u; } v; v.h = h; return v.u;
}

// ws layout: [0, 512K) W'^T bf16 ; [512K, 640K) P bias partials f32 [64][512]
#define WS_WPT 0
#define WS_P   524288

// ---------------------------------------------------------------------------
// blocks 0..63   : W'^T[n'][k'] = sum_m Wo[m][n'] * Wv[k'][m]   (bf16 out)
// blocks 64..127 : bias partials P[j][n] = sum_{m in 8j..8j+7} bv[m]*Wo[m][n]
// blocks 128..255: prefetch x (warm L2/L3 for the gemm that follows)
// ---------------------------------------------------------------------------
__global__ __launch_bounds__(256)
void precompose_fused(const float* __restrict__ Wv, const float* __restrict__ bv,
                      const float* __restrict__ Wo, const float* __restrict__ x,
                      u16* __restrict__ WpT, float* __restrict__ P) {
  const int b = blockIdx.x;
  const int tid = threadIdx.x;

  if (b >= 128) {             // ---- x prefetch: 128 rows per block
    const int j = b - 128;
    const float* base = x + (size_t)j * 128 * 512;
    f32x4 s = {0.f, 0.f, 0.f, 0.f};
#pragma unroll 8
    for (int it = 0; it < 64; ++it) {
      f32x4 v = *(const f32x4*)(base + (size_t)(it * 256 + tid) * 4);
      s[0] += v[0]; s[1] += v[1]; s[2] += v[2]; s[3] += v[3];
    }
    // data-dependent never-true sink: compiler must keep the loads
    if (s[0] == 1.2345678e30f && s[1] == -s[2] && s[3] == 9.87e21f && tid == 255)
      P[32768 + b] = s[0];
    return;
  }

  if (b >= 64) {              // ---- bias partials (parallel over m-slices)
    const int j = b - 64;
    const int n = tid;
    float s0 = 0.f, s1 = 0.f;
#pragma unroll
    for (int mm = 0; mm < 8; ++mm) {
      const float bvm = bv[8 * j + mm];
      const float* w = Wo + (size_t)(8 * j + mm) * 512;
      s0 += bvm * w[n];
      s1 += bvm * w[n + 256];
    }
    P[(size_t)j * 512 + n] = s0;
    P[(size_t)j * 512 + n + 256] = s1;
    return;
  }

  // ---- W'^T 64x64 tile
  __shared__ u16 As[64 * 72];          // As[n'loc][mloc], stride 72
  __shared__ u16 Bs[64 * 72];          // Bs[k'loc][mloc], stride 72
  const int lane = tid & 63, wave = tid >> 6;
  const int wm = wave & 1, wn = wave >> 1;
  const int q = lane >> 4, lr = lane & 15;
  const int i0 = (b >> 3) * 64;        // n' tile
  const int j0 = (b & 7) * 64;         // k' tile

  f32x4 acc[2][2];
#pragma unroll
  for (int i = 0; i < 2; ++i)
#pragma unroll
    for (int j = 0; j < 2; ++j) { f32x4 z = {0.f,0.f,0.f,0.f}; acc[i][j] = z; }

  for (int m0 = 0; m0 < 512; m0 += 64) {
#pragma unroll
    for (int su = 0; su < 4; ++su) {   // transposed A stage, f32x4 loads
      const int s = su * 256 + tid;    // 0..1023
      const int mloc = s >> 4;         // 0..63
      const int nq = (s & 15) * 4;     // 0,4,..,60
      f32x4 w = *(const f32x4*)(Wo + (size_t)(m0 + mloc) * 512 + i0 + nq);
#pragma unroll
      for (int e = 0; e < 4; ++e)
        As[(nq + e) * 72 + mloc] = f2bf(w[e]);
    }
#pragma unroll
    for (int su = 0; su < 2; ++su) {   // B stage (vectorized)
      const int s = su * 256 + tid;
      const int row = s >> 3, p = s & 7;
      const float* sv = Wv + (size_t)(j0 + row) * 512 + m0 + p * 8;
      f32x4 a = *(const f32x4*)sv, c4 = *(const f32x4*)(sv + 4);
      ushort8 o;
      o[0]=f2bf(a[0]); o[1]=f2bf(a[1]); o[2]=f2bf(a[2]); o[3]=f2bf(a[3]);
      o[4]=f2bf(c4[0]); o[5]=f2bf(c4[1]); o[6]=f2bf(c4[2]); o[7]=f2bf(c4[3]);
      *(ushort8*)(Bs + row * 72 + p * 8) = o;
    }
    __syncthreads();

#pragma unroll
    for (int kk = 0; kk < 2; ++kk) {
      const int c = kk * 4 + q;
      bf16x8 af[2], bfr[2];
#pragma unroll
      for (int t = 0; t < 2; ++t) {
        af[t]  = *(const bf16x8*)(As + (wm * 32 + t * 16 + lr) * 72 + c * 8);
        bfr[t] = *(const bf16x8*)(Bs + (wn * 32 + t * 16 + lr) * 72 + c * 8);
      }
#pragma unroll
      for (int mt = 0; mt < 2; ++mt)
#pragma unroll
        for (int nt = 0; nt < 2; ++nt)
          acc[mt][nt] = __builtin_amdgcn_mfma_f32_16x16x32_bf16(
              af[mt], bfr[nt], acc[mt][nt], 0, 0, 0);
    }
    __syncthreads();
  }

  // D: col=lane&15, row=quad*4+reg
#pragma unroll
  for (int nt = 0; nt < 2; ++nt) {
    const int col = j0 + wn * 32 + nt * 16 + lr;
#pragma unroll
    for (int mt = 0; mt < 2; ++mt) {
      const int row0 = i0 + wm * 32 + mt * 16 + q * 4;
#pragma unroll
      for (int r = 0; r < 4; ++r)
        WpT[(size_t)(row0 + r) * 512 + col] = f2bf(acc[mt][nt][r]);
    }
  }
}

// ---------------------------------------------------------------------------
// out[M,512] f32 = x[M,512] f32 @ W' (+ b'), W' as BT[n][k] bf16.
// 64x128 tile (BM=64 rows, BN=128 cols), BK=64. Grid 1024 (1-D):
//   m_idx = bid & 255, n_idx = bid >> 8  => the 4 n-blocks of an m-slab are
//   ids {m, m+256, m+512, m+768}: same id%8 => same XCD (x reuse in L2).
// 4 blocks/CU (launch_bounds(256,4), LDS 24.5 KB, VGPR<=128) = 4 waves/SIMD
// for latency hiding. Register prefetch, 2 barriers/iter (R5 structure).
// C written with nontemporal stores (never re-read; keep L2 for x).
// ---------------------------------------------------------------------------
__global__ __launch_bounds__(256, 4)
void gemm_x_bt(const float* __restrict__ x, const u16* __restrict__ BT,
               const float* __restrict__ P, const float* __restrict__ bo,
               float* __restrict__ C) {
  constexpr int BM = 64, BN = 128, BK = 64;
  __shared__ u16 As[BM * BK];          // x-tile bf16, XOR-swizzled chunks
  __shared__ u16 Bs[BN * BK];          // W'^T tile
  __shared__ float bias_s[BN];

  const int tid = threadIdx.x;
  const int lane = tid & 63, wave = tid >> 6;
  const int wm = wave & 1, wn = wave >> 1;
  const int q = lane >> 4, lr = lane & 15;
  const int bid = blockIdx.x;
  const int m0 = (bid & 255) * BM;
  const int n0 = (bid >> 8) * BN;

  f32x4 acc[2][4];
#pragma unroll
  for (int i = 0; i < 2; ++i)
#pragma unroll
    for (int j = 0; j < 4; ++j) { f32x4 z = {0.f,0.f,0.f,0.f}; acc[i][j] = z; }

  f32x4 pa0[2], pa1[2];            // prefetched x (2 slots/thread)
  ushort8 pb[4];                   // prefetched BT (4 slots/thread)

  auto load_tile = [&](int k0) {
#pragma unroll
    for (int it = 0; it < 2; ++it) {           // A: 512 slots
      const int s = it * 256 + tid;
      const int row = s >> 3, p = s & 7;
      const int c = p ^ (row & 7);
      const float* sx = x + (size_t)(m0 + row) * 512 + k0 + c * 8;
      pa0[it] = *(const f32x4*)sx;
      pa1[it] = *(const f32x4*)(sx + 4);
    }
#pragma unroll
    for (int it = 0; it < 4; ++it) {           // B: 1024 slots
      const int s = it * 256 + tid;
      const int row = s >> 3, p = s & 7;
      const int c = p ^ (row & 7);
      pb[it] = *(const ushort8*)(BT + (size_t)(n0 + row) * 512 + k0 + c * 8);
    }
  };
  auto store_tile = [&]() {
#pragma unroll
    for (int it = 0; it < 2; ++it) {
      const int s = it * 256 + tid;
      ushort8 o;
      o[0]=f2bf(pa0[it][0]); o[1]=f2bf(pa0[it][1]);
      o[2]=f2bf(pa0[it][2]); o[3]=f2bf(pa0[it][3]);
      o[4]=f2bf(pa1[it][0]); o[5]=f2bf(pa1[it][1]);
      o[6]=f2bf(pa1[it][2]); o[7]=f2bf(pa1[it][3]);
      *(ushort8*)(As + s * 8) = o;
    }
#pragma unroll
    for (int it = 0; it < 4; ++it) {
      const int s = it * 256 + tid;
      *(ushort8*)(Bs + s * 8) = pb[it];
    }
  };
  auto compute = [&]() {
#pragma unroll
    for (int kk = 0; kk < 2; ++kk) {
      const int c = kk * 4 + q;
      bf16x8 af[2], bfr[4];
#pragma unroll
      for (int t = 0; t < 2; ++t) {
        const int rowA = wm * 32 + t * 16 + lr;
        af[t] = *(const bf16x8*)(As + rowA * BK + (c ^ (rowA & 7)) * 8);
      }
#pragma unroll
      for (int t = 0; t < 4; ++t) {
        const int rowB = wn * 64 + t * 16 + lr;
        bfr[t] = *(const bf16x8*)(Bs + rowB * BK + (c ^ (rowB & 7)) * 8);
      }
#pragma unroll
      for (int mt = 0; mt < 2; ++mt)
#pragma unroll
        for (int nt = 0; nt < 4; ++nt)
          acc[mt][nt] = __builtin_amdgcn_mfma_f32_16x16x32_bf16(
              af[mt], bfr[nt], acc[mt][nt], 0, 0, 0);
    }
  };

  // prologue: issue tile-0 loads; overlap bias reduction with them
  load_tile(0);
  if (tid < BN) {
    float s = bo[n0 + tid];
#pragma unroll 8
    for (int j = 0; j < 64; ++j) s += P[(size_t)j * 512 + n0 + tid];
    bias_s[tid] = s;
  }
  store_tile();
  __syncthreads();

  for (int k = 1; k < 8; ++k) {
    load_tile(k * 64);             // next tile in flight during compute
    compute();
    __syncthreads();               // all waves done reading LDS
    store_tile();
    __syncthreads();
  }
  compute();

  // D: col=lane&15, row=quad*4+reg; nontemporal f32 stores
#pragma unroll
  for (int nt = 0; nt < 4; ++nt) {
    const int lcol = wn * 64 + nt * 16 + lr;
    const float bsv = bias_s[lcol];
#pragma unroll
    for (int mt = 0; mt < 2; ++mt) {
      const int grow0 = m0 + wm * 32 + mt * 16 + q * 4;
#pragma unroll
      for (int r = 0; r < 4; ++r)
        __builtin_nontemporal_store(acc[mt][nt][r] + bsv,
                                    C + (size_t)(grow0 + r) * 512 + n0 + lcol);
    }
  }
}

// ---------------------------------------------------------------------------
extern "C" void kernel_launch(void* const* d_in, const int* in_sizes, int n_in,
                              void* d_out, int out_size, void* d_ws, size_t ws_size,
                              hipStream_t stream) {
  // 0:x 1:H 2:W 3:Wq 4:bq 5:Wk 6:bk 7:Wv 8:bv 9:Wo 10:bo 11..14 offsets(dead)
  const float* x  = (const float*)d_in[0];
  const float* Wv = (const float*)d_in[7];
  const float* bv = (const float*)d_in[8];
  const float* Wo = (const float*)d_in[9];
  const float* bo = (const float*)d_in[10];
  float* outp = (float*)d_out;

  u16*   WpT = (u16*)((uint8_t*)d_ws + WS_WPT);
  float* P   = (float*)((uint8_t*)d_ws + WS_P);

  precompose_fused<<<256, 256, 0, stream>>>(Wv, bv, Wo, x, WpT, P);
  gemm_x_bt<<<1024, 256, 0, stream>>>(x, WpT, P, bo, outp);
}